// Round 12
// baseline (363.424 us; speedup 1.0000x reference)
//
#include <hip/hip_runtime.h>

// FloodPath R14b: single fused kernel — ballot-staging directly from input.
//   (Resubmission of R14; round 11 failed on container infra, not the kernel.)
//   R13 proved staging-gather latency was the bottleneck (transposed planes:
//   controllable 109 -> 96us). R14 removes the pack pass entirely: each wave
//   ballots its 64x64 window straight from flood_input (lane = column, 64
//   row-iterations of {512B-contiguous float2 load, 2 ballots, select}).
//   No workspace, no launch gap, no grid.sync (R11's failure), no funnel
//   shifts. Input logically read 4x but fits L3 (134MB < 256MB); XCD band
//   swizzle keeps each XCD's band (~17MB) cache-resident -> HBM FETCH stays
//   ~input+fc. Input loads PLAIN (cacheable), fc NT (read-once), output
//   plain packed dwordx4 (R12). Kept: wave 64x64 register window, 16 shfl
//   dilation steps, bit-sliced counters, cross-wave plane transpose,
//   lockstep packed store phase, fc prefetch hoisted.

typedef unsigned long long u64;
typedef float f32x4 __attribute__((ext_vector_type(4)));
typedef float f32x2 __attribute__((ext_vector_type(2)));

#define HH 4096
#define WW 4096
#define NSTEPS 16
#define HALO 16
#define IT 32             // interior tile side per wave (64x64 window)

__global__ __launch_bounds__(256, 8) void flood_kernel(
    const float* __restrict__ flood_input,
    const float* __restrict__ flood_count,
    float* __restrict__ out)
{
    // cross-wave transpose planes: [wave][interior row][occ,f,c0..4] — 7168 B
    __shared__ u64 plane[4][IT][7];
    // per-wave packed output staging: 2 rows x 128 px x 3 ch — 12288 B
    __shared__ float out2[4][2 * 128 * 3];

    const int tid  = threadIdx.x;
    const int lane = tid & 63;
    const int wv   = tid >> 6;

    // ---- Bijective XCD band swizzle (4096 blocks, gridDim = 32 x 128).
    const int wgid = blockIdx.y * 32 + blockIdx.x;   // 0..4095
    const int nl   = (wgid & 7) * 512 + (wgid >> 3); // chunk per XCD
    const int bx   = nl & 31;
    const int by   = nl >> 5;

    const int tile_r0 = by * IT;                     // 0..4064
    const int tile_c0 = bx * (4 * IT) + wv * IT;     // wave's 32 cols
    const int bc0     = bx * (4 * IT);               // block col start

    // ---- fc prefetch for output iteration 0 (issue before staging).
    const int half = lane >> 5;                  // 0 or 1: row within pair
    const int l32  = lane & 31;
    const int col0 = l32 * 4;                    // block-local col of 4 px
    const float* fcbase = flood_count +
        (size_t)(tile_r0 + wv * 8 + half) * WW + bc0 + col0;
    f32x4 fc_next = __builtin_nontemporal_load((const f32x4*)fcbase);

    // ---- Ballot-stage the 64x64 window directly from flood_input.
    //      Lane samples column gc = tile_c0-16+lane; row j's ballot word
    //      lands in lane j's registers (occ, f).
    const int gc   = tile_c0 - HALO + lane;
    const bool cin = (gc >= 0) & (gc < WW);
    const int gcc  = min(max(gc, 0), WW - 1);
    const u64 colmask = __ballot(cin);           // valid-column mask
    const int r0 = tile_r0 - HALO;
    const float* ibase = flood_input + (size_t)gcc * 2;

    u64 occ = 0, f = 0;
#pragma unroll 1
    for (int jb = 0; jb < 64; jb += 4) {
        f32x2 v[4];
#pragma unroll
        for (int j = 0; j < 4; ++j) {
            const int gr  = r0 + jb + j;
            const int grc = min(max(gr, 0), HH - 1);
            v[j] = *(const f32x2*)(ibase + (size_t)grc * (WW * 2));
        }
#pragma unroll
        for (int j = 0; j < 4; ++j) {
            const int gr = r0 + jb + j;          // wave-uniform
            u64 om = __ballot(v[j][0] > 0.5f);
            u64 fm = __ballot(v[j][1] > 0.5f);
            om |= ~colmask;                      // OOB cols => wall
            fm &= colmask;
            if (gr < 0 || gr >= HH) { om = ~0ull; fm = 0ull; }  // uniform
            const bool mine = (lane == jb + j);
            occ = mine ? om : occ;
            f   = mine ? fm : f;
        }
    }

    // ---- 16 dilation steps, fully in registers. No barriers.
    const u64 nocc = ~occ;
    u64 c0 = 0, c1 = 0, c2 = 0, c3 = 0, c4 = 0;
#pragma unroll
    for (int it = 0; it < NSTEPS; ++it) {
        u64 up = __shfl_up(f, 1);
        u64 dn = __shfl_down(f, 1);
        if (lane == 0)  up = 0ull;
        if (lane == 63) dn = 0ull;
        f = nocc & (f | (f << 1) | (f >> 1) | up | dn);
        u64 c = f, t;
        t = c0; c0 = t ^ c; c = t & c;
        t = c1; c1 = t ^ c; c = t & c;
        t = c2; c2 = t ^ c; c = t & c;
        t = c3; c3 = t ^ c; c = t & c;
        c4 ^= c;                                 // max 16: no carry out
    }

    // ---- Cross-wave transpose: lanes 16..47 hold interior rows.
    if (lane >= HALO && lane < HALO + IT) {
        u64* p = plane[wv][lane - HALO];
        p[0] = occ; p[1] = f;
        p[2] = c0; p[3] = c1; p[4] = c2; p[5] = c3; p[6] = c4;
    }
    __syncthreads();

    // ---- Output: wave wv owns interior rows wv*8..wv*8+7, full 128-col
    //      width, as 4 row-pairs.
    const int sw   = col0 >> 5;                  // source wave for my 4 px
    const int bit0 = HALO + (col0 & 31);
    for (int t = 0; t < 4; ++t) {
        const f32x4 fc4 = fc_next;
        if (t + 1 < 4)
            fc_next = __builtin_nontemporal_load(
                (const f32x4*)(fcbase + (size_t)(t + 1) * 2 * WW));

        const int rA   = wv * 8 + 2 * t;         // pair's first interior row
        const int irow = rA + half;              // this lane's interior row
        const u64* p = plane[sw][irow];
        const u64 ow = p[0], fw = p[1];
        const u64 k0 = p[2], k1 = p[3], k2 = p[4], k3 = p[5], k4 = p[6];

        float v[12];
#pragma unroll
        for (int j = 0; j < 4; ++j) {
            const int bit = bit0 + j;
            int cv = (int)((k0 >> bit) & 1ull)
                   + ((int)((k1 >> bit) & 1ull) << 1)
                   + ((int)((k2 >> bit) & 1ull) << 2)
                   + ((int)((k3 >> bit) & 1ull) << 3)
                   + ((int)((k4 >> bit) & 1ull) << 4);
            v[j*3+0] = (float)((ow >> bit) & 1ull);
            v[j*3+1] = (float)((fw >> bit) & 1ull);
            v[j*3+2] = (float)cv + fc4[j];
        }
        // stage: byte offset = half*1536 + l32*48 (16B aligned, lane-linear)
        float* dst = &out2[wv][half * 384 + l32 * 12];
        *(f32x4*)(dst + 0) = (f32x4){v[0], v[1], v[2],  v[3]};
        *(f32x4*)(dst + 4) = (f32x4){v[4], v[5], v[6],  v[7]};
        *(f32x4*)(dst + 8) = (f32x4){v[8], v[9], v[10], v[11]};

        __syncthreads();   // lockstep store phase

        // read back linearly, 3 packed plain dwordx4 stores per lane
#pragma unroll
        for (int st = 0; st < 3; ++st) {
            const int L   = st * 256 + lane * 4;   // float idx in 768-float pair
            const int row = (L >= 384) ? 1 : 0;
            const int off = L - row * 384;
            const f32x4 q = *(const f32x4*)(&out2[wv][L]);
            *(f32x4*)(out + ((size_t)(tile_r0 + rA + row) * WW + bc0) * 3
                      + off) = q;
        }
    }
}

extern "C" void kernel_launch(void* const* d_in, const int* in_sizes, int n_in,
                              void* d_out, int out_size, void* d_ws, size_t ws_size,
                              hipStream_t stream) {
    const float* flood_input = (const float*)d_in[0];  // [4096][4096][2]
    const float* flood_cnt   = (const float*)d_in[1];  // [4096][4096]
    float* out = (float*)d_out;                        // [4096][4096][3]

    dim3 grid(WW / (4 * IT), HH / IT);                 // 32 x 128 = 4096 blocks
    flood_kernel<<<grid, dim3(256), 0, stream>>>(flood_input, flood_cnt, out);
}

// Round 13
// 343.940 us; speedup vs baseline: 1.0567x; 1.0567x over previous
//
#include <hip/hip_runtime.h>

// FloodPath R15: R13 (best: 345.5, controllable ~96us) + interleaved planes.
//   R14's fused ballot-staging regressed (126us flood, VALU-bound 41%):
//   128 ballots + 128 selects per wave cost more than the pack pass saved.
//   Reverted to R13's two-kernel transposed-plane structure and applied one
//   micro-fix: occ/fl planes interleaved as u64x2 in pT[word][row][2], so
//   flood staging = 2x dwordx4 loads (16B/lane, wave = 1KB contiguous per
//   instruction, was 4x dwordx2) and pack = 1x 16B store per lane (was 2x).
//   Kept from R13: transposed word-major planes (the staging-gather fix that
//   broke the 109-115us plateau), XCD band swizzle, NT loads for read-once
//   streams, fc prefetch one iteration ahead, plain packed dwordx4 output
//   stores, cross-wave plane transpose + lockstep store phase.

typedef unsigned long long u64;
typedef unsigned long long u64x2 __attribute__((ext_vector_type(2)));
typedef float f32x4 __attribute__((ext_vector_type(4)));
typedef float f32x2 __attribute__((ext_vector_type(2)));

#define HH 4096
#define WW 4096
#define WPR 64            // u64 words per image row
#define NSTEPS 16
#define HALO 16
#define IT 32             // interior tile side per wave (64x64 window)

// ---------------- Kernel 1: bitpack (transposed, interleaved) ----------------
//   Block = 64 rows x 4 word-columns (one per wave). Grid = 64*16 = 1024.
//   Wave wv: for r in 0..63 load row (r0+r), word w; ballot; lane0 -> LDS.
//   Then one contiguous 1KB column store: pT[w][r0+lane] = {occ, fl}.
__global__ __launch_bounds__(256) void pack_kernel(
    const float* __restrict__ flood_input,
    u64* __restrict__ pT)
{
    __shared__ u64 lb[4][64][2];                 // [wave][row][plane] 4 KiB

    const int lane = threadIdx.x & 63;
    const int wv   = threadIdx.x >> 6;
    const int r0   = (blockIdx.x >> 4) * 64;     // row group
    const int w    = (blockIdx.x & 15) * 4 + wv; // word column 0..63

    const float* src = flood_input +
        ((size_t)r0 * WW + (w << 6) + lane) * 2;
#pragma unroll 4
    for (int rb = 0; rb < 64; rb += 8) {
        float vx[8], vy[8];
#pragma unroll
        for (int j = 0; j < 8; ++j) {
            const f32x2 v = __builtin_nontemporal_load(
                (const f32x2*)(src + (size_t)(rb + j) * (WW * 2)));
            vx[j] = v[0]; vy[j] = v[1];
        }
#pragma unroll
        for (int j = 0; j < 8; ++j) {
            const u64 om = __ballot(vx[j] > 0.5f);
            const u64 fm = __ballot(vy[j] > 0.5f);
            if (lane == 0) {
                lb[wv][rb + j][0] = om;
                lb[wv][rb + j][1] = fm;
            }
        }
    }
    // lb[wv][*] is wave-private (written and read by wave wv only).
    asm volatile("s_waitcnt lgkmcnt(0)" ::: "memory");
    const u64x2 q = *(const u64x2*)&lb[wv][lane][0];
    *(u64x2*)(pT + ((size_t)w * HH + r0 + lane) * 2) = q;
}

// ---------------- Kernel 2: flood + count + output ----------------
__global__ __launch_bounds__(256, 8) void flood_kernel(
    const u64* __restrict__ pT,
    const float* __restrict__ flood_count,
    float* __restrict__ out)
{
    // cross-wave transpose planes: [wave][interior row][occ,f,c0..4] — 7168 B
    __shared__ u64 plane[4][IT][7];
    // per-wave packed output staging: 2 rows x 128 px x 3 ch — 12288 B
    __shared__ float out2[4][2 * 128 * 3];

    const int tid  = threadIdx.x;
    const int lane = tid & 63;
    const int wv   = tid >> 6;

    // ---- Bijective XCD band swizzle (4096 blocks, gridDim = 32 x 128).
    const int wgid = blockIdx.y * 32 + blockIdx.x;   // 0..4095
    const int nl   = (wgid & 7) * 512 + (wgid >> 3); // chunk per XCD
    const int bx   = nl & 31;
    const int by   = nl >> 5;

    const int tile_r0 = by * IT;                     // 0..4064
    const int tile_c0 = bx * (4 * IT) + wv * IT;     // wave's 32 cols
    const int bc0     = bx * (4 * IT);               // block col start

    // ---- Stage window from interleaved transposed planes:
    //      2x dwordx4 loads, each wave-contiguous 1KB.
    const int gr   = tile_r0 - HALO + lane;
    const bool rin = (gr >= 0) & (gr < HH);
    const int grc  = min(max(gr, 0), HH - 1);
    const int s    = tile_c0 - HALO;             // >= -16
    const int q0   = ((s + 64) >> 6) - 1;        // floor(s/64)
    const int sh   = s - (q0 << 6);              // 16 or 48

    const bool va = rin & (q0 >= 0);
    const bool vb = rin & (q0 + 1 < WPR);
    const int qa = max(q0, 0);
    const int qb = min(q0 + 1, WPR - 1);
    const u64x2 A = *(const u64x2*)(pT + ((size_t)qa * HH + grc) * 2);
    const u64x2 B = *(const u64x2*)(pT + ((size_t)qb * HH + grc) * 2);
    u64 o0 = A[0], f0 = A[1], o1 = B[0], f1 = B[1];
    if (!va) { o0 = ~0ull; f0 = 0ull; }          // OOB => wall, no flood
    if (!vb) { o1 = ~0ull; f1 = 0ull; }
    const u64 occ = (o0 >> sh) | (sh ? (o1 << (64 - sh)) : 0ull);
    u64       f   = (f0 >> sh) | (sh ? (f1 << (64 - sh)) : 0ull);

    // ---- fc prefetch for output iteration 0 (hides under dilation VALU).
    const int half = lane >> 5;                  // 0 or 1: row within pair
    const int l32  = lane & 31;
    const int col0 = l32 * 4;                    // block-local col of 4 px
    const float* fcbase = flood_count +
        (size_t)(tile_r0 + wv * 8 + half) * WW + bc0 + col0;
    f32x4 fc_next = __builtin_nontemporal_load((const f32x4*)fcbase);

    // ---- 16 dilation steps, fully in registers. No barriers.
    const u64 nocc = ~occ;
    u64 c0 = 0, c1 = 0, c2 = 0, c3 = 0, c4 = 0;
#pragma unroll
    for (int it = 0; it < NSTEPS; ++it) {
        u64 up = __shfl_up(f, 1);
        u64 dn = __shfl_down(f, 1);
        if (lane == 0)  up = 0ull;
        if (lane == 63) dn = 0ull;
        f = nocc & (f | (f << 1) | (f >> 1) | up | dn);
        u64 c = f, t;
        t = c0; c0 = t ^ c; c = t & c;
        t = c1; c1 = t ^ c; c = t & c;
        t = c2; c2 = t ^ c; c = t & c;
        t = c3; c3 = t ^ c; c = t & c;
        c4 ^= c;                                 // max 16: no carry out
    }

    // ---- Cross-wave transpose: lanes 16..47 hold interior rows.
    if (lane >= HALO && lane < HALO + IT) {
        u64* p = plane[wv][lane - HALO];
        p[0] = occ; p[1] = f;
        p[2] = c0; p[3] = c1; p[4] = c2; p[5] = c3; p[6] = c4;
    }
    __syncthreads();

    // ---- Output: wave wv owns interior rows wv*8..wv*8+7, full 128-col
    //      width, as 4 row-pairs.
    const int sw   = col0 >> 5;                  // source wave for my 4 px
    const int bit0 = HALO + (col0 & 31);
    for (int t = 0; t < 4; ++t) {
        const f32x4 fc4 = fc_next;
        if (t + 1 < 4)
            fc_next = __builtin_nontemporal_load(
                (const f32x4*)(fcbase + (size_t)(t + 1) * 2 * WW));

        const int rA   = wv * 8 + 2 * t;         // pair's first interior row
        const int irow = rA + half;              // this lane's interior row
        const u64* p = plane[sw][irow];
        const u64 ow = p[0], fw = p[1];
        const u64 k0 = p[2], k1 = p[3], k2 = p[4], k3 = p[5], k4 = p[6];

        float v[12];
#pragma unroll
        for (int j = 0; j < 4; ++j) {
            const int bit = bit0 + j;
            int cv = (int)((k0 >> bit) & 1ull)
                   + ((int)((k1 >> bit) & 1ull) << 1)
                   + ((int)((k2 >> bit) & 1ull) << 2)
                   + ((int)((k3 >> bit) & 1ull) << 3)
                   + ((int)((k4 >> bit) & 1ull) << 4);
            v[j*3+0] = (float)((ow >> bit) & 1ull);
            v[j*3+1] = (float)((fw >> bit) & 1ull);
            v[j*3+2] = (float)cv + fc4[j];
        }
        // stage: byte offset = half*1536 + l32*48 (16B aligned, lane-linear)
        float* dst = &out2[wv][half * 384 + l32 * 12];
        *(f32x4*)(dst + 0) = (f32x4){v[0], v[1], v[2],  v[3]};
        *(f32x4*)(dst + 4) = (f32x4){v[4], v[5], v[6],  v[7]};
        *(f32x4*)(dst + 8) = (f32x4){v[8], v[9], v[10], v[11]};

        __syncthreads();   // lockstep store phase

        // read back linearly, 3 packed plain dwordx4 stores per lane
#pragma unroll
        for (int st = 0; st < 3; ++st) {
            const int L   = st * 256 + lane * 4;   // float idx in 768-float pair
            const int row = (L >= 384) ? 1 : 0;
            const int off = L - row * 384;
            const f32x4 q = *(const f32x4*)(&out2[wv][L]);
            *(f32x4*)(out + ((size_t)(tile_r0 + rA + row) * WW + bc0) * 3
                      + off) = q;
        }
    }
}

extern "C" void kernel_launch(void* const* d_in, const int* in_sizes, int n_in,
                              void* d_out, int out_size, void* d_ws, size_t ws_size,
                              hipStream_t stream) {
    const float* flood_input = (const float*)d_in[0];  // [4096][4096][2]
    const float* flood_cnt   = (const float*)d_in[1];  // [4096][4096]
    float* out = (float*)d_out;                        // [4096][4096][3]

    u64* pT = (u64*)d_ws;                              // 4 MiB, [word][row][2]

    pack_kernel<<<dim3(64 * 16), dim3(256), 0, stream>>>(flood_input, pT);

    dim3 grid(WW / (4 * IT), HH / IT);                 // 32 x 128 = 4096 blocks
    flood_kernel<<<grid, dim3(256), 0, stream>>>(pT, flood_cnt, out);
}